// Round 5
// baseline (7746.181 us; speedup 1.0000x reference)
//
#include <hip/hip_runtime.h>

#define B_ 128
#define T_ 1024
#define I_ 256
#define H_ 512
#define O_ 128

#define BGROUPS 4
#define ROWS 32                   // batch rows per block
#define CGROUPS 32
#define HC 16                     // h-cols per block
#define NBLK (BGROUPS*CGROUPS)    // 128
#define NTHR 512                  // 8 waves: (mt 0..1) x (kq 0..3)

#define HSLAB64 (B_*(H_/2))       // u64 per h slab: 32768
#define WS_INIT_BYTES (2*HSLAB64*8)   // 524288

#define LDS_BYTES 32768           // 4 C-slabs x 8KB, linear frag layout

typedef __attribute__((ext_vector_type(8))) short short8;
typedef __attribute__((ext_vector_type(4))) float f32x4;

__device__ __forceinline__ unsigned int bf16rne(float f) {
    unsigned int u = __builtin_bit_cast(unsigned int, f);
    u += 0x7fffu + ((u >> 16) & 1u);
    return u >> 16;
}
__device__ __forceinline__ short8 pack8(float4 a, float4 b) {
    short8 r;
    r[0]=(short)bf16rne(a.x); r[1]=(short)bf16rne(a.y); r[2]=(short)bf16rne(a.z); r[3]=(short)bf16rne(a.w);
    r[4]=(short)bf16rne(b.x); r[5]=(short)bf16rne(b.y); r[6]=(short)bf16rne(b.z); r[7]=(short)bf16rne(b.w);
    return r;
}
__device__ __forceinline__ short8 cvt8(const float* p) {
    return pack8(*(const float4*)p, *(const float4*)(p + 4));
}
__device__ __forceinline__ unsigned long long ald64(const unsigned long long* p) {
    return __hip_atomic_load(p, __ATOMIC_RELAXED, __HIP_MEMORY_SCOPE_AGENT);
}

__global__ __launch_bounds__(NTHR, 1)
void gru_mfma(const float* __restrict__ x,
              const float* __restrict__ Wih,
              const float* __restrict__ Whh,
              const float* __restrict__ bih,
              const float* __restrict__ bhh,
              unsigned long long* __restrict__ hslab)  // [2][128][256] u64 {2xbf16, epoch}
{
    __shared__ __align__(16) char smem[LDS_BYTES];

    const int tid  = threadIdx.x;
    const int lane = tid & 63;
    const int g    = blockIdx.x >> 5;          // batch group 0..3
    const int cg   = blockIdx.x & 31;          // column group 0..31
    const int rb0  = g * ROWS;
    const int hc0  = cg * HC;

    const int wv = tid >> 6;                   // 0..7
    const int mt = wv & 1;                     // M-tile (16 rows)
    const int kq = wv >> 1;                    // K-quarter

    // ---- one-time: weight B-fragments into registers ----
    short8 BX[2][3], BH[4][3];
#pragma unroll
    for (int xk = 0; xk < 2; ++xk) {
        int kb = (kq * 2 + xk) * 32 + ((lane >> 4) << 3);
#pragma unroll
        for (int nt = 0; nt < 3; ++nt)
            BX[xk][nt] = cvt8(Wih + (nt * H_ + hc0 + (lane & 15)) * I_ + kb);
    }
#pragma unroll
    for (int hk = 0; hk < 4; ++hk) {
        int kb = (kq * 4 + hk) * 32 + ((lane >> 4) << 3);
#pragma unroll
        for (int nt = 0; nt < 3; ++nt)
            BH[hk][nt] = cvt8(Whh + (nt * H_ + hc0 + (lane & 15)) * H_ + kb);
    }

    // A-frag geometry for this lane
    const int arow = rb0 + mt * 16 + (lane & 15);
    const int kch  = lane >> 4;                // k-chunk 0..3

    // finalize constants: thread owns output (frow, fcl)
    const int frow = tid >> 4;                 // 0..31
    const int fcl  = tid & 15;                 // 0..15
    const int j    = hc0 + fcl;
    const float bR  = bih[j] + bhh[j];
    const float bZ  = bih[H_ + j] + bhh[H_ + j];
    const float bNx = bih[2 * H_ + j];
    const float bNh = bhh[2 * H_ + j];
    const int mtf  = frow >> 4;
    const int r16  = frow & 15;
    const int fbase = ((((r16 >> 2) << 4) | fcl) << 2) + (r16 & 3);   // lane'*4 + reg
    float hprev = 0.f;

    // x prefetch pointers (this wave's own 2 k-slices, 8 floats each)
    const float* xp0 = x + (arow * T_) * I_ + (kq * 2) * 32 + kch * 8;
    const float* xp1 = xp0 + 32;
    float4 pxa0 = *(const float4*)xp0, pxa1 = *(const float4*)(xp0 + 4);
    float4 pxb0 = *(const float4*)xp1, pxb1 = *(const float4*)(xp1 + 4);
    xp0 += I_; xp1 += I_;

    // h fragment base offsets (u64 index within a slab)
    const int hfo = arow * (H_ / 2) + kch * 4;   // + (kq*4+hk)*16 + s

#pragma unroll 1
    for (int t = 0; t < T_; ++t) {
        // ---- poll-load own h fragments (epoch == t means fresh) ----
        const unsigned long long* hb64 = hslab + (t & 1) * HSLAB64 + hfo;
        const unsigned int want = (unsigned int)t;
        unsigned long long v[16];
#pragma unroll
        for (int hk = 0; hk < 4; ++hk) {
            const unsigned long long* p = hb64 + (kq * 4 + hk) * 16;
            v[4*hk+0] = ald64(p + 0);
            v[4*hk+1] = ald64(p + 1);
            v[4*hk+2] = ald64(p + 2);
            v[4*hk+3] = ald64(p + 3);
        }
        for (;;) {
            bool ok = true;
#pragma unroll
            for (int i = 0; i < 16; ++i)
                if ((unsigned int)(v[i] >> 32) != want) ok = false;
            if (ok) break;
#pragma unroll
            for (int i = 0; i < 16; ++i)
                if ((unsigned int)(v[i] >> 32) != want)
                    v[i] = ald64(hb64 + ((i >> 2) + kq * 4) * 16 + (i & 3));
        }

        // ---- MFMA: x part then h part ----
        f32x4 accR = {0.f, 0.f, 0.f, 0.f}, accZ = accR, accNX = accR, accNH = accR;
        {
            short8 ax0 = pack8(pxa0, pxa1);
            short8 ax1 = pack8(pxb0, pxb1);
            accR  = __builtin_amdgcn_mfma_f32_16x16x32_bf16(ax0, BX[0][0], accR, 0, 0, 0);
            accZ  = __builtin_amdgcn_mfma_f32_16x16x32_bf16(ax0, BX[0][1], accZ, 0, 0, 0);
            accNX = __builtin_amdgcn_mfma_f32_16x16x32_bf16(ax0, BX[0][2], accNX, 0, 0, 0);
            accR  = __builtin_amdgcn_mfma_f32_16x16x32_bf16(ax1, BX[1][0], accR, 0, 0, 0);
            accZ  = __builtin_amdgcn_mfma_f32_16x16x32_bf16(ax1, BX[1][1], accZ, 0, 0, 0);
            accNX = __builtin_amdgcn_mfma_f32_16x16x32_bf16(ax1, BX[1][2], accNX, 0, 0, 0);
        }
#pragma unroll
        for (int hk = 0; hk < 4; ++hk) {
            union { unsigned int w[4]; short8 s; } u;
            u.w[0] = (unsigned int)v[4*hk+0];
            u.w[1] = (unsigned int)v[4*hk+1];
            u.w[2] = (unsigned int)v[4*hk+2];
            u.w[3] = (unsigned int)v[4*hk+3];
            accR  = __builtin_amdgcn_mfma_f32_16x16x32_bf16(u.s, BH[hk][0], accR, 0, 0, 0);
            accZ  = __builtin_amdgcn_mfma_f32_16x16x32_bf16(u.s, BH[hk][1], accZ, 0, 0, 0);
            accNH = __builtin_amdgcn_mfma_f32_16x16x32_bf16(u.s, BH[hk][2], accNH, 0, 0, 0);
        }

        // ---- protect LDS (prev finalize reads done); drain hides under poll ----
        __syncthreads();
        {
            char* cb = smem + wv * 1024 + lane * 16;
            *(f32x4*)(cb +     0) = accR;
            *(f32x4*)(cb +  8192) = accZ;
            *(f32x4*)(cb + 16384) = accNX;
            *(f32x4*)(cb + 24576) = accNH;
        }
        __syncthreads();

        // ---- finalize: sum 4 K-quarters, gates, store {bf16 pair, epoch t+1} ----
        {
            const float* CB = (const float*)smem;
            float sr = bR, sz = bZ, sxn = bNx, shn = bNh;
#pragma unroll
            for (int q = 0; q < 4; ++q) {
                int base = (q * 2 + mtf) * 256 + fbase;
                sr  += CB[base];
                sz  += CB[2048 + base];
                sxn += CB[4096 + base];
                shn += CB[6144 + base];
            }
            float r = 1.f / (1.f + __expf(-sr));
            float z = 1.f / (1.f + __expf(-sz));
            float e2 = __expf(2.f * (sxn + r * shn));
            float n = 1.f - 2.f / (e2 + 1.f);          // tanh, overflow-safe
            float hnew = (1.f - z) * n + z * hprev;
            hprev = hnew;
            unsigned int hb = bf16rne(hnew);
            unsigned int ob = (unsigned int)__shfl_xor((int)hb, 1);
            if (!(fcl & 1)) {
                unsigned long long pk = (unsigned long long)((hb & 0xffffu) | ((ob & 0xffffu) << 16))
                                      | ((unsigned long long)(unsigned int)(t + 1) << 32);
                __hip_atomic_store(hslab + ((t + 1) & 1) * HSLAB64 + (rb0 + frow) * (H_ / 2) + (j >> 1),
                                   pk, __ATOMIC_RELAXED, __HIP_MEMORY_SCOPE_AGENT);
            }
        }

        // ---- prefetch x(t+1); latency hides under next step's poll ----
        if (t + 1 < T_) {
            pxa0 = *(const float4*)xp0; pxa1 = *(const float4*)(xp0 + 4);
            pxb0 = *(const float4*)xp1; pxb1 = *(const float4*)(xp1 + 4);
            xp0 += I_; xp1 += I_;
        }
    }
}

__global__ __launch_bounds__(256)
void fc_kernel(const unsigned long long* __restrict__ hp,  // hslab[0]: [128][256] u64
               const float* __restrict__ fcW,
               const float* __restrict__ fcb,
               float* __restrict__ out)
{
    int gid = blockIdx.x * 256 + threadIdx.x;
    int b = gid >> 7, o = gid & 127;
    const unsigned long long* hr = hp + b * (H_ / 2);
    const float* wr = fcW + o * H_;
    float acc = 0.f;
#pragma unroll 8
    for (int i = 0; i < H_ / 2; i += 2) {
        uint4 v = *(const uint4*)(hr + i);     // 2 u64: lo words = bf16 pairs
        float4 w = *(const float4*)(wr + 2 * i);
        acc += __builtin_bit_cast(float, v.x << 16)          * w.x
             + __builtin_bit_cast(float, v.x & 0xffff0000u)  * w.y
             + __builtin_bit_cast(float, v.z << 16)          * w.z
             + __builtin_bit_cast(float, v.z & 0xffff0000u)  * w.w;
    }
    out[gid] = acc + fcb[o];
}

extern "C" void kernel_launch(void* const* d_in, const int* in_sizes, int n_in,
                              void* d_out, int out_size, void* d_ws, size_t ws_size,
                              hipStream_t stream)
{
    const float* x   = (const float*)d_in[0];
    const float* Wih = (const float*)d_in[1];
    const float* Whh = (const float*)d_in[2];
    const float* bih = (const float*)d_in[3];
    const float* bhh = (const float*)d_in[4];
    const float* fcW = (const float*)d_in[5];
    const float* fcb = (const float*)d_in[6];
    float* out = (float*)d_out;

    unsigned long long* hslab = (unsigned long long*)d_ws;   // [2][128][256] u64

    hipMemsetAsync(d_ws, 0, WS_INIT_BYTES, stream);   // h0 = 0 with epoch 0 (every replay)

    hipLaunchKernelGGL(gru_mfma, dim3(NBLK), dim3(NTHR), 0, stream,
                       x, Wih, Whh, bih, bhh, hslab);

    hipLaunchKernelGGL(fc_kernel, dim3((B_ * O_) / 256), dim3(256), 0, stream,
                       hslab, fcW, fcb, out);         // final h is slab 0 (T even)
}

// Round 6
// 7069.328 us; speedup vs baseline: 1.0957x; 1.0957x over previous
//
#include <hip/hip_runtime.h>

#define B_ 128
#define T_ 1024
#define I_ 256
#define H_ 512
#define O_ 128

#define BGROUPS 4
#define ROWS 32                   // batch rows per block
#define CGROUPS 32
#define HC 16                     // h-cols per block
#define NBLK (BGROUPS*CGROUPS)    // 128
#define NTHR 512                  // 8 waves: (mt 0..1) x (kq 0..3)

#define HSLAB64 (B_*(H_/2))       // u64 per h slab: 32768
#define WS_INIT_BYTES (2*HSLAB64*8 + T_*BGROUPS*CGROUPS*4)   // 512KB + 512KB

#define LDS_BYTES 32768           // 4 C-slabs x 8KB, linear frag layout

typedef __attribute__((ext_vector_type(8))) short short8;
typedef __attribute__((ext_vector_type(4))) float f32x4;

__device__ __forceinline__ unsigned int bf16rne(float f) {
    unsigned int u = __builtin_bit_cast(unsigned int, f);
    u += 0x7fffu + ((u >> 16) & 1u);
    return u >> 16;
}
__device__ __forceinline__ short8 pack8(float4 a, float4 b) {
    short8 r;
    r[0]=(short)bf16rne(a.x); r[1]=(short)bf16rne(a.y); r[2]=(short)bf16rne(a.z); r[3]=(short)bf16rne(a.w);
    r[4]=(short)bf16rne(b.x); r[5]=(short)bf16rne(b.y); r[6]=(short)bf16rne(b.z); r[7]=(short)bf16rne(b.w);
    return r;
}
__device__ __forceinline__ short8 cvt8(const float* p) {
    return pack8(*(const float4*)p, *(const float4*)(p + 4));
}
__device__ __forceinline__ unsigned long long ald64(const unsigned long long* p) {
    return __hip_atomic_load(p, __ATOMIC_RELAXED, __HIP_MEMORY_SCOPE_AGENT);
}

__global__ __launch_bounds__(NTHR, 1)
void gru_mfma(const float* __restrict__ x,
              const float* __restrict__ Wih,
              const float* __restrict__ Whh,
              const float* __restrict__ bih,
              const float* __restrict__ bhh,
              unsigned long long* __restrict__ hslab,  // [2][128][256] u64 {2xbf16, epoch}
              unsigned int* __restrict__ flags)        // [1024][4][32]
{
    __shared__ __align__(16) char smem[LDS_BYTES];

    const int tid  = threadIdx.x;
    const int lane = tid & 63;
    const int g    = blockIdx.x >> 5;          // batch group 0..3
    const int cg   = blockIdx.x & 31;          // column group 0..31
    const int rb0  = g * ROWS;
    const int hc0  = cg * HC;

    const int wv = tid >> 6;                   // 0..7
    const int mt = wv & 1;                     // M-tile (16 rows)
    const int kq = wv >> 1;                    // K-quarter

    // ---- one-time: weight B-fragments into registers ----
    short8 BX[2][3], BH[4][3];
#pragma unroll
    for (int xk = 0; xk < 2; ++xk) {
        int kb = (kq * 2 + xk) * 32 + ((lane >> 4) << 3);
#pragma unroll
        for (int nt = 0; nt < 3; ++nt)
            BX[xk][nt] = cvt8(Wih + (nt * H_ + hc0 + (lane & 15)) * I_ + kb);
    }
#pragma unroll
    for (int hk = 0; hk < 4; ++hk) {
        int kb = (kq * 4 + hk) * 32 + ((lane >> 4) << 3);
#pragma unroll
        for (int nt = 0; nt < 3; ++nt)
            BH[hk][nt] = cvt8(Whh + (nt * H_ + hc0 + (lane & 15)) * H_ + kb);
    }

    // A-frag geometry for this lane
    const int arow = rb0 + mt * 16 + (lane & 15);
    const int kch  = lane >> 4;                // k-chunk 0..3

    // finalize constants: thread owns output (frow, fcl)
    const int frow = tid >> 4;                 // 0..31
    const int fcl  = tid & 15;                 // 0..15
    const int j    = hc0 + fcl;
    const float bR  = bih[j] + bhh[j];
    const float bZ  = bih[H_ + j] + bhh[H_ + j];
    const float bNx = bih[2 * H_ + j];
    const float bNh = bhh[2 * H_ + j];
    const int mtf  = frow >> 4;
    const int r16  = frow & 15;
    const int fbase = ((((r16 >> 2) << 4) | fcl) << 2) + (r16 & 3);   // lane'*4 + reg
    float hprev = 0.f;

    // x prefetch pointers (this wave's own 2 k-slices, 8 floats each)
    const float* xp0 = x + (arow * T_) * I_ + (kq * 2) * 32 + kch * 8;
    const float* xp1 = xp0 + 32;
    float4 pxa0 = *(const float4*)xp0, pxa1 = *(const float4*)(xp0 + 4);
    float4 pxb0 = *(const float4*)xp1, pxb1 = *(const float4*)(xp1 + 4);
    xp0 += I_; xp1 += I_;

    // h fragment base offset (u64 index within a slab)
    const int hfo = arow * (H_ / 2) + kch * 4;

    // prologue: speculative h loads for t=0 (memset slab: epoch 0 == want 0)
    const unsigned long long* hb64 = hslab + hfo;   // slab parity 0
    unsigned long long v[16];
#pragma unroll
    for (int hk = 0; hk < 4; ++hk) {
        const unsigned long long* p = hb64 + (kq * 4 + hk) * 16;
        v[4*hk+0] = ald64(p + 0); v[4*hk+1] = ald64(p + 1);
        v[4*hk+2] = ald64(p + 2); v[4*hk+3] = ald64(p + 3);
    }

#pragma unroll 1
    for (int t = 0; t < T_; ++t) {
        // ---- A: wave0 polls group flags from step t-1 (hint; epochs authoritative) ----
        if (t > 0 && tid < 64) {
            const unsigned int* fl = flags + ((t - 1) * BGROUPS + g) * CGROUPS;
            unsigned int fv;
            do {
                fv = __hip_atomic_load(fl + (lane & 31), __ATOMIC_RELAXED, __HIP_MEMORY_SCOPE_AGENT);
            } while (!__all((int)(fv != 0)));
        }
        __builtin_amdgcn_s_barrier();

        // ---- D: x-part MFMAs (prefetched regs; runs while h words settle) ----
        f32x4 accR = {0.f, 0.f, 0.f, 0.f}, accZ = accR, accNX = accR, accNH = accR;
        {
            short8 ax0 = pack8(pxa0, pxa1);
            short8 ax1 = pack8(pxb0, pxb1);
            accR  = __builtin_amdgcn_mfma_f32_16x16x32_bf16(ax0, BX[0][0], accR, 0, 0, 0);
            accZ  = __builtin_amdgcn_mfma_f32_16x16x32_bf16(ax0, BX[0][1], accZ, 0, 0, 0);
            accNX = __builtin_amdgcn_mfma_f32_16x16x32_bf16(ax0, BX[0][2], accNX, 0, 0, 0);
            accR  = __builtin_amdgcn_mfma_f32_16x16x32_bf16(ax1, BX[1][0], accR, 0, 0, 0);
            accZ  = __builtin_amdgcn_mfma_f32_16x16x32_bf16(ax1, BX[1][1], accZ, 0, 0, 0);
            accNX = __builtin_amdgcn_mfma_f32_16x16x32_bf16(ax1, BX[1][2], accNX, 0, 0, 0);
        }

        // ---- C: validate speculative h loads (epoch == t); rare bounded retry ----
        {
            const unsigned int want = (unsigned int)t;
            for (;;) {
                unsigned int bad = 0;
#pragma unroll
                for (int i = 0; i < 16; ++i)
                    bad |= ((unsigned int)(v[i] >> 32)) ^ want;
                if (!__any((int)(bad != 0))) break;
#pragma unroll
                for (int i = 0; i < 16; ++i)
                    if ((unsigned int)(v[i] >> 32) != want)
                        v[i] = ald64(hb64 + (kq * 4 + (i >> 2)) * 16 + (i & 3));
                __builtin_amdgcn_s_sleep(1);
            }
        }

        // ---- E: h-part MFMAs ----
#pragma unroll
        for (int hk = 0; hk < 4; ++hk) {
            union { unsigned int w[4]; short8 s; } u;
            u.w[0] = (unsigned int)v[4*hk+0];
            u.w[1] = (unsigned int)v[4*hk+1];
            u.w[2] = (unsigned int)v[4*hk+2];
            u.w[3] = (unsigned int)v[4*hk+3];
            accR  = __builtin_amdgcn_mfma_f32_16x16x32_bf16(u.s, BH[hk][0], accR, 0, 0, 0);
            accZ  = __builtin_amdgcn_mfma_f32_16x16x32_bf16(u.s, BH[hk][1], accZ, 0, 0, 0);
            accNH = __builtin_amdgcn_mfma_f32_16x16x32_bf16(u.s, BH[hk][2], accNH, 0, 0, 0);
        }

        // ---- dump partials (WAR safe: barrier pair since prior finalize reads) ----
        {
            char* cb = smem + wv * 1024 + lane * 16;
            *(f32x4*)(cb +     0) = accR;
            *(f32x4*)(cb +  8192) = accZ;
            *(f32x4*)(cb + 16384) = accNX;
            *(f32x4*)(cb + 24576) = accNH;
        }
        __syncthreads();

        // ---- finalize: sum K-quarters, gates, store {bf16 pair, epoch t+1} ----
        {
            const float* CB = (const float*)smem;
            float sr = bR, sz = bZ, sxn = bNx, shn = bNh;
#pragma unroll
            for (int q = 0; q < 4; ++q) {
                int base = (q * 2 + mtf) * 256 + fbase;
                sr  += CB[base];
                sz  += CB[2048 + base];
                sxn += CB[4096 + base];
                shn += CB[6144 + base];
            }
            float r = 1.f / (1.f + __expf(-sr));
            float z = 1.f / (1.f + __expf(-sz));
            float e2 = __expf(2.f * (sxn + r * shn));
            float n = 1.f - 2.f / (e2 + 1.f);          // tanh, overflow-safe
            float hnew = (1.f - z) * n + z * hprev;
            hprev = hnew;
            unsigned int hb = bf16rne(hnew);
            unsigned int ob = (unsigned int)__shfl_xor((int)hb, 1);
            if (!(fcl & 1)) {
                unsigned long long pk = (unsigned long long)((hb & 0xffffu) | ((ob & 0xffffu) << 16))
                                      | ((unsigned long long)(unsigned int)(t + 1) << 32);
                __hip_atomic_store(hslab + ((t + 1) & 1) * HSLAB64 + (rb0 + frow) * (H_ / 2) + (j >> 1),
                                   pk, __ATOMIC_RELAXED, __HIP_MEMORY_SCOPE_AGENT);
            }
        }

        // ---- signal (no drain: stores issued; epochs validate) ----
        __builtin_amdgcn_s_barrier();
        if (tid == 0)
            __hip_atomic_store(flags + (t * BGROUPS + g) * CGROUPS + cg, 1u,
                               __ATOMIC_RELAXED, __HIP_MEMORY_SCOPE_AGENT);

        // ---- J/K: speculative h loads + x prefetch for t+1 (fly under detect) ----
        if (t + 1 < T_) {
            hb64 = hslab + ((t + 1) & 1) * HSLAB64 + hfo;
#pragma unroll
            for (int hk = 0; hk < 4; ++hk) {
                const unsigned long long* p = hb64 + (kq * 4 + hk) * 16;
                v[4*hk+0] = ald64(p + 0); v[4*hk+1] = ald64(p + 1);
                v[4*hk+2] = ald64(p + 2); v[4*hk+3] = ald64(p + 3);
            }
            pxa0 = *(const float4*)xp0; pxa1 = *(const float4*)(xp0 + 4);
            pxb0 = *(const float4*)xp1; pxb1 = *(const float4*)(xp1 + 4);
            xp0 += I_; xp1 += I_;
        }
    }
}

__global__ __launch_bounds__(256)
void fc_kernel(const unsigned long long* __restrict__ hp,  // hslab[0]: [128][256] u64
               const float* __restrict__ fcW,
               const float* __restrict__ fcb,
               float* __restrict__ out)
{
    int gid = blockIdx.x * 256 + threadIdx.x;
    int b = gid >> 7, o = gid & 127;
    const unsigned long long* hr = hp + b * (H_ / 2);
    const float* wr = fcW + o * H_;
    float acc = 0.f;
#pragma unroll 8
    for (int i = 0; i < H_ / 2; i += 2) {
        uint4 v = *(const uint4*)(hr + i);     // 2 u64: lo words = bf16 pairs
        float4 w = *(const float4*)(wr + 2 * i);
        acc += __builtin_bit_cast(float, v.x << 16)          * w.x
             + __builtin_bit_cast(float, v.x & 0xffff0000u)  * w.y
             + __builtin_bit_cast(float, v.z << 16)          * w.z
             + __builtin_bit_cast(float, v.z & 0xffff0000u)  * w.w;
    }
    out[gid] = acc + fcb[o];
}

extern "C" void kernel_launch(void* const* d_in, const int* in_sizes, int n_in,
                              void* d_out, int out_size, void* d_ws, size_t ws_size,
                              hipStream_t stream)
{
    const float* x   = (const float*)d_in[0];
    const float* Wih = (const float*)d_in[1];
    const float* Whh = (const float*)d_in[2];
    const float* bih = (const float*)d_in[3];
    const float* bhh = (const float*)d_in[4];
    const float* fcW = (const float*)d_in[5];
    const float* fcb = (const float*)d_in[6];
    float* out = (float*)d_out;

    unsigned long long* hslab = (unsigned long long*)d_ws;          // [2][128][256] u64
    unsigned int* flags = (unsigned int*)(hslab + 2 * HSLAB64);     // [1024][4][32]

    hipMemsetAsync(d_ws, 0, WS_INIT_BYTES, stream);   // h0 = 0 epoch 0, flags = 0 (every replay)

    hipLaunchKernelGGL(gru_mfma, dim3(NBLK), dim3(NTHR), 0, stream,
                       x, Wih, Whh, bih, bhh, hslab, flags);

    hipLaunchKernelGGL(fc_kernel, dim3((B_ * O_) / 256), dim3(256), 0, stream,
                       hslab, fcW, fcb, out);         // final h is slab 0 (T even)
}

// Round 7
// 6468.490 us; speedup vs baseline: 1.1975x; 1.0929x over previous
//
#include <hip/hip_runtime.h>

#define B_ 128
#define T_ 1024
#define I_ 256
#define H_ 512
#define O_ 128

#define BGROUPS 8
#define ROWS 16                   // batch rows per block (one M-tile)
#define CGROUPS 16
#define HC 32                     // h-cols per block
#define NBLK (BGROUPS*CGROUPS)    // 128
#define NTHR 512                  // 8 waves: (kq 0..3) x (nh 0..1)

#define HSLAB64 (B_*(H_/2))       // u64 per h slab: 32768
#define WS_INIT_BYTES (2*HSLAB64*8 + T_*BGROUPS*CGROUPS*4)   // 512KB + 512KB

#define LDS_BYTES 32768           // 4 C-slabs x 8KB, linear frag layout

typedef __attribute__((ext_vector_type(8))) short short8;
typedef __attribute__((ext_vector_type(4))) float f32x4;

__device__ __forceinline__ unsigned int bf16rne(float f) {
    unsigned int u = __builtin_bit_cast(unsigned int, f);
    u += 0x7fffu + ((u >> 16) & 1u);
    return u >> 16;
}
__device__ __forceinline__ short8 pack8(float4 a, float4 b) {
    short8 r;
    r[0]=(short)bf16rne(a.x); r[1]=(short)bf16rne(a.y); r[2]=(short)bf16rne(a.z); r[3]=(short)bf16rne(a.w);
    r[4]=(short)bf16rne(b.x); r[5]=(short)bf16rne(b.y); r[6]=(short)bf16rne(b.z); r[7]=(short)bf16rne(b.w);
    return r;
}
__device__ __forceinline__ short8 cvt8(const float* p) {
    return pack8(*(const float4*)p, *(const float4*)(p + 4));
}
__device__ __forceinline__ unsigned long long ald64(const unsigned long long* p) {
    return __hip_atomic_load(p, __ATOMIC_RELAXED, __HIP_MEMORY_SCOPE_AGENT);
}

__global__ __launch_bounds__(NTHR, 1)
void gru_mfma(const float* __restrict__ x,
              const float* __restrict__ Wih,
              const float* __restrict__ Whh,
              const float* __restrict__ bih,
              const float* __restrict__ bhh,
              unsigned long long* __restrict__ hslab,  // [2][128][256] u64 {2xbf16, epoch}
              unsigned int* __restrict__ flags)        // [1024][8][16]
{
    __shared__ __align__(16) char smem[LDS_BYTES];

    const int tid  = threadIdx.x;
    const int lane = tid & 63;
    const int g    = blockIdx.x >> 4;          // batch group 0..7
    const int cg   = blockIdx.x & 15;          // column group 0..15
    const int rb0  = g * ROWS;
    const int hc0  = cg * HC;

    const int wv = tid >> 6;                   // 0..7
    const int nh = wv & 1;                     // N-half (16 cols)
    const int kq = wv >> 1;                    // K-quarter

    // ---- one-time: weight B-fragments into registers ----
    // B-frag(kt, gate): lane l holds W[gate*H + hc0 + nh*16 + (l&15)][kt*32 + (l>>4)*8 ..+8]
    const int colb = hc0 + nh * 16 + (lane & 15);
    short8 BX[2][3], BH[4][3];
#pragma unroll
    for (int xk = 0; xk < 2; ++xk) {
        int kb = kq * 64 + xk * 32 + ((lane >> 4) << 3);
#pragma unroll
        for (int nt = 0; nt < 3; ++nt)
            BX[xk][nt] = cvt8(Wih + (nt * H_ + colb) * I_ + kb);
    }
#pragma unroll
    for (int hk = 0; hk < 4; ++hk) {
        int kb = kq * 128 + hk * 32 + ((lane >> 4) << 3);
#pragma unroll
        for (int nt = 0; nt < 3; ++nt)
            BH[hk][nt] = cvt8(Whh + (nt * H_ + colb) * H_ + kb);
    }

    // A-frag geometry: single M-tile of 16 rows
    const int arow = rb0 + (lane & 15);
    const int kch  = lane >> 4;                // k-chunk 0..3

    // finalize constants: thread owns output (frow, fcl)
    const int frow = tid >> 5;                 // 0..15
    const int fcl  = tid & 31;                 // 0..31
    const int j    = hc0 + fcl;
    const float bR  = bih[j] + bhh[j];
    const float bZ  = bih[H_ + j] + bhh[H_ + j];
    const float bNx = bih[2 * H_ + j];
    const float bNh = bhh[2 * H_ + j];
    const int nh_f = fcl >> 4;
    const int c16  = fcl & 15;
    const int fbase = (((frow >> 2) << 4) + c16) * 4 + (frow & 3);   // float idx in 256-slab
    float hprev = 0.f;

    // x prefetch pointers (this wave's own 2 k-slices, 8 floats each)
    const float* xp0 = x + (arow * T_) * I_ + kq * 64 + kch * 8;
    const float* xp1 = xp0 + 32;
    float4 pxa0 = *(const float4*)xp0, pxa1 = *(const float4*)(xp0 + 4);
    float4 pxb0 = *(const float4*)xp1, pxb1 = *(const float4*)(xp1 + 4);
    xp0 += I_; xp1 += I_;

    // h fragment base offset (u64 index within a slab)
    const int hfo = arow * (H_ / 2) + kch * 4;

#pragma unroll 1
    for (int t = 0; t < T_; ++t) {
        // ---- A: wave0 polls group flags from step t-1 ----
        if (t > 0 && tid < 64) {
            const unsigned int* fl = flags + ((t - 1) * BGROUPS + g) * CGROUPS;
            unsigned int fv;
            do {
                fv = __hip_atomic_load(fl + (lane & 15), __ATOMIC_RELAXED, __HIP_MEMORY_SCOPE_AGENT);
            } while (!__all((int)(fv != 0)));
        }
        __builtin_amdgcn_s_barrier();

        // ---- B: issue h fragment loads (after detect -> data already landed) ----
        const unsigned long long* hb64 = hslab + (t & 1) * HSLAB64 + hfo;
        unsigned long long v[16];
#pragma unroll
        for (int hk = 0; hk < 4; ++hk) {
            const unsigned long long* p = hb64 + (kq * 4 + hk) * 16;
            v[4*hk+0] = ald64(p + 0); v[4*hk+1] = ald64(p + 1);
            v[4*hk+2] = ald64(p + 2); v[4*hk+3] = ald64(p + 3);
        }

        // ---- C: x-part MFMAs while h loads fly ----
        f32x4 accR = {0.f, 0.f, 0.f, 0.f}, accZ = accR, accNX = accR, accNH = accR;
        {
            short8 ax0 = pack8(pxa0, pxa1);
            short8 ax1 = pack8(pxb0, pxb1);
            accR  = __builtin_amdgcn_mfma_f32_16x16x32_bf16(ax0, BX[0][0], accR, 0, 0, 0);
            accZ  = __builtin_amdgcn_mfma_f32_16x16x32_bf16(ax0, BX[0][1], accZ, 0, 0, 0);
            accNX = __builtin_amdgcn_mfma_f32_16x16x32_bf16(ax0, BX[0][2], accNX, 0, 0, 0);
            accR  = __builtin_amdgcn_mfma_f32_16x16x32_bf16(ax1, BX[1][0], accR, 0, 0, 0);
            accZ  = __builtin_amdgcn_mfma_f32_16x16x32_bf16(ax1, BX[1][1], accZ, 0, 0, 0);
            accNX = __builtin_amdgcn_mfma_f32_16x16x32_bf16(ax1, BX[1][2], accNX, 0, 0, 0);
        }

        // ---- D: validate epochs (safety net for the no-drain race; rare retry) ----
        {
            const unsigned int want = (unsigned int)t;
            for (;;) {
                unsigned int bad = 0;
#pragma unroll
                for (int i = 0; i < 16; ++i)
                    bad |= ((unsigned int)(v[i] >> 32)) ^ want;
                if (!__any((int)(bad != 0))) break;
#pragma unroll
                for (int i = 0; i < 16; ++i)
                    if ((unsigned int)(v[i] >> 32) != want)
                        v[i] = ald64(hb64 + (kq * 4 + (i >> 2)) * 16 + (i & 3));
                __builtin_amdgcn_s_sleep(1);
            }
        }

        // ---- E: h-part MFMAs ----
#pragma unroll
        for (int hk = 0; hk < 4; ++hk) {
            union { unsigned int w[4]; short8 s; } u;
            u.w[0] = (unsigned int)v[4*hk+0];
            u.w[1] = (unsigned int)v[4*hk+1];
            u.w[2] = (unsigned int)v[4*hk+2];
            u.w[3] = (unsigned int)v[4*hk+3];
            accR  = __builtin_amdgcn_mfma_f32_16x16x32_bf16(u.s, BH[hk][0], accR, 0, 0, 0);
            accZ  = __builtin_amdgcn_mfma_f32_16x16x32_bf16(u.s, BH[hk][1], accZ, 0, 0, 0);
            accNH = __builtin_amdgcn_mfma_f32_16x16x32_bf16(u.s, BH[hk][2], accNH, 0, 0, 0);
        }

        // ---- F: dump partials (WAR safe via end-barrier(t-1) + A-barrier(t)) ----
        {
            char* cb = smem + wv * 1024 + lane * 16;
            *(f32x4*)(cb +     0) = accR;
            *(f32x4*)(cb +  8192) = accZ;
            *(f32x4*)(cb + 16384) = accNX;
            *(f32x4*)(cb + 24576) = accNH;
        }
        __syncthreads();

        // ---- G: finalize: sum 4 K-quarters, gates, store {bf16 pair, epoch t+1} ----
        {
            const float* CB = (const float*)smem;
            float sr = bR, sz = bZ, sxn = bNx, shn = bNh;
#pragma unroll
            for (int q = 0; q < 4; ++q) {
                int base = (q * 2 + nh_f) * 256 + fbase;
                sr  += CB[base];
                sz  += CB[2048 + base];
                sxn += CB[4096 + base];
                shn += CB[6144 + base];
            }
            float r = 1.f / (1.f + __expf(-sr));
            float z = 1.f / (1.f + __expf(-sz));
            float e2 = __expf(2.f * (sxn + r * shn));
            float n = 1.f - 2.f / (e2 + 1.f);          // tanh, overflow-safe
            float hnew = (1.f - z) * n + z * hprev;
            hprev = hnew;
            unsigned int hb = bf16rne(hnew);
            unsigned int ob = (unsigned int)__shfl_xor((int)hb, 1);
            if (!(fcl & 1)) {
                unsigned long long pk = (unsigned long long)((hb & 0xffffu) | ((ob & 0xffffu) << 16))
                                      | ((unsigned long long)(unsigned int)(t + 1) << 32);
                __hip_atomic_store(hslab + ((t + 1) & 1) * HSLAB64 + (rb0 + frow) * (H_ / 2) + (j >> 1),
                                   pk, __ATOMIC_RELAXED, __HIP_MEMORY_SCOPE_AGENT);
            }
        }

        // ---- H: signal early (no vmcnt drain; epochs authoritative) ----
        __builtin_amdgcn_s_barrier();          // all waves have ISSUED their h stores
        if (tid == 0)
            __hip_atomic_store(flags + (t * BGROUPS + g) * CGROUPS + cg, 1u,
                               __ATOMIC_RELAXED, __HIP_MEMORY_SCOPE_AGENT);

        // ---- I: prefetch x(t+1); latency hides under next poll ----
        if (t + 1 < T_) {
            pxa0 = *(const float4*)xp0; pxa1 = *(const float4*)(xp0 + 4);
            pxb0 = *(const float4*)xp1; pxb1 = *(const float4*)(xp1 + 4);
            xp0 += I_; xp1 += I_;
        }
    }
}

__global__ __launch_bounds__(256)
void fc_kernel(const unsigned long long* __restrict__ hp,  // hslab[0]: [128][256] u64
               const float* __restrict__ fcW,
               const float* __restrict__ fcb,
               float* __restrict__ out)
{
    int gid = blockIdx.x * 256 + threadIdx.x;
    int b = gid >> 7, o = gid & 127;
    const unsigned long long* hr = hp + b * (H_ / 2);
    const float* wr = fcW + o * H_;
    float acc = 0.f;
#pragma unroll 8
    for (int i = 0; i < H_ / 2; i += 2) {
        uint4 v = *(const uint4*)(hr + i);     // 2 u64: lo words = bf16 pairs
        float4 w = *(const float4*)(wr + 2 * i);
        acc += __builtin_bit_cast(float, v.x << 16)          * w.x
             + __builtin_bit_cast(float, v.x & 0xffff0000u)  * w.y
             + __builtin_bit_cast(float, v.z << 16)          * w.z
             + __builtin_bit_cast(float, v.z & 0xffff0000u)  * w.w;
    }
    out[gid] = acc + fcb[o];
}

extern "C" void kernel_launch(void* const* d_in, const int* in_sizes, int n_in,
                              void* d_out, int out_size, void* d_ws, size_t ws_size,
                              hipStream_t stream)
{
    const float* x   = (const float*)d_in[0];
    const float* Wih = (const float*)d_in[1];
    const float* Whh = (const float*)d_in[2];
    const float* bih = (const float*)d_in[3];
    const float* bhh = (const float*)d_in[4];
    const float* fcW = (const float*)d_in[5];
    const float* fcb = (const float*)d_in[6];
    float* out = (float*)d_out;

    unsigned long long* hslab = (unsigned long long*)d_ws;          // [2][128][256] u64
    unsigned int* flags = (unsigned int*)(hslab + 2 * HSLAB64);     // [1024][8][16]

    hipMemsetAsync(d_ws, 0, WS_INIT_BYTES, stream);   // h0 = 0 epoch 0, flags = 0 (every replay)

    hipLaunchKernelGGL(gru_mfma, dim3(NBLK), dim3(NTHR), 0, stream,
                       x, Wih, Whh, bih, bhh, hslab, flags);

    hipLaunchKernelGGL(fc_kernel, dim3((B_ * O_) / 256), dim3(256), 0, stream,
                       hslab, fcW, fcb, out);         // final h is slab 0 (T even)
}